// Round 7
// baseline (335.299 us; speedup 1.0000x reference)
//
#include <hip/hip_runtime.h>
#include <hip/hip_bf16.h>
#include <cstdint>
#include <cstddef>

typedef __attribute__((ext_vector_type(8))) short bf16x8;
typedef __attribute__((ext_vector_type(4))) short bf16x4;
typedef __attribute__((ext_vector_type(4))) float f32x4;
typedef __attribute__((ext_vector_type(2))) unsigned int u32x2;
typedef __attribute__((ext_vector_type(4))) unsigned int u32x4;

#define NH 16
#define DK 64
#define SEQ 2048
#define DM 1024
#define QSCALE 0.18033688011112042f  // 0.125 * log2(e): softmax uses exp2

// RTNE (cvt kernels, VALU free there)
__device__ __forceinline__ short f2bf(float f) {
    union { float f; unsigned u; } x; x.f = f;
    unsigned r = x.u + 0x7fffu + ((x.u >> 16) & 1u);
    return (short)(r >> 16);
}

// fast pack: two f32 -> bf16 pair (round-half-up), one v_perm_b32
__device__ __forceinline__ unsigned pk2(float a, float b) {
    union { float f; unsigned u; } x, y; x.f = a; y.f = b;
    return __builtin_amdgcn_perm(y.u + 0x8000u, x.u + 0x8000u, 0x07060302u);
}

// single-instruction pack: dst.lo16 = bf16(a), dst.hi16 = bf16(b)
__device__ __forceinline__ unsigned cvtpk(float a, float b) {
    unsigned r;
    asm("v_cvt_pk_bf16_f32 %0, %1, %2" : "=v"(r) : "v"(a), "v"(b));
    return r;
}

// gfx950 cross-lane swap (HW direction verified via HK T12 recipe):
// a lanes[32:63] <-> b lanes[0:31]; after: a = (a_lo, b_lo), b = (a_hi, b_hi)
__device__ __forceinline__ void plswap32(unsigned& a, unsigned& b) {
    asm("v_permlane32_swap_b32 %0, %1" : "+v"(a), "+v"(b));
}

__device__ __forceinline__ void glds16(const short* g, short* l) {
    __builtin_amdgcn_global_load_lds((const __attribute__((address_space(1))) unsigned int*)g,
                                     (__attribute__((address_space(3))) unsigned int*)l, 16, 0, 0);
}

// ---------------------------------------------------------------------------
// fused fp32->bf16 conversion: 3 x-inputs (4096 blocks each) + 4 weights (512 each)
// ---------------------------------------------------------------------------
__global__ __launch_bounds__(256)
void cvt_all(const float* __restrict__ xq, const float* __restrict__ xk, const float* __restrict__ xv,
             const float* __restrict__ Wq, const float* __restrict__ Wk,
             const float* __restrict__ Wv, const float* __restrict__ Wo,
             short* __restrict__ xb0, short* __restrict__ xb1, short* __restrict__ xb2,
             short* __restrict__ Wb)
{
    const int bid = blockIdx.x;
    const float* src;
    short* dst;
    float sc = 1.0f;
    int i;
    if (bid < 12288) {
        int z = bid >> 12;
        src = (z == 0) ? xq : (z == 1) ? xk : xv;
        dst = (z == 0) ? xb0 : (z == 1) ? xb1 : xb2;
        i = (bid & 4095) * 2048 + threadIdx.x * 8;
    } else {
        int wb = bid - 12288;
        int z = wb >> 9;
        src = (z == 0) ? Wq : (z == 1) ? Wk : (z == 2) ? Wv : Wo;
        dst = Wb + (size_t)z * DM * DM;
        sc = (z == 0) ? QSCALE : 1.0f;  // fold q scale into Wq
        i = (wb & 511) * 2048 + threadIdx.x * 8;
    }
    float4 a = *(const float4*)&src[i];
    float4 b = *(const float4*)&src[i + 4];
    bf16x8 o = { f2bf(a.x * sc), f2bf(a.y * sc), f2bf(a.z * sc), f2bf(a.w * sc),
                 f2bf(b.x * sc), f2bf(b.y * sc), f2bf(b.z * sc), f2bf(b.w * sc) };
    *(bf16x8*)&dst[i] = o;
}

// fallback converters (sequential path)
__global__ __launch_bounds__(256)
void cvt_x(const float* __restrict__ src, short* __restrict__ dst)
{
    int i = (blockIdx.x * 256 + threadIdx.x) * 8;
    float4 a = *(const float4*)&src[i];
    float4 b = *(const float4*)&src[i + 4];
    bf16x8 o = { f2bf(a.x), f2bf(a.y), f2bf(a.z), f2bf(a.w),
                 f2bf(b.x), f2bf(b.y), f2bf(b.z), f2bf(b.w) };
    *(bf16x8*)&dst[i] = o;
}

__global__ __launch_bounds__(256)
void cvt_w(const float* __restrict__ Wq, const float* __restrict__ Wk,
           const float* __restrict__ Wv, const float* __restrict__ Wo,
           short* __restrict__ dst)
{
    int z = blockIdx.y;
    const float* s = (z == 0) ? Wq : (z == 1) ? Wk : (z == 2) ? Wv : Wo;
    float sc = (z == 0) ? QSCALE : 1.0f;
    int i = (blockIdx.x * 256 + threadIdx.x) * 8;
    float4 a = *(const float4*)&s[i];
    float4 b = *(const float4*)&s[i + 4];
    bf16x8 o = { f2bf(a.x * sc), f2bf(a.y * sc), f2bf(a.z * sc), f2bf(a.w * sc),
                 f2bf(b.x * sc), f2bf(b.y * sc), f2bf(b.z * sc), f2bf(b.w * sc) };
    *(bf16x8*)&dst[(size_t)z * DM * DM + i] = o;
}

// ---------------------------------------------------------------------------
// bf16 GEMM core: 128x128 tile, BK=32, global_load_lds width=16, XOR swizzle.
// Single-buffer, 2 barriers/K-step (r2-proven; explicit dbuf regressed: LDS
// doubling halved block residency and TLP was doing the latency hiding).
// ---------------------------------------------------------------------------
#define GEMM_CORE(P0, OFF0, P1, OFF1)                                                      \
    __shared__ short As[128 * 32];                                                         \
    __shared__ short Bs[128 * 32];                                                         \
    f32x4 acc[4][4] = {};                                                                  \
    const int t = threadIdx.x;                                                             \
    const int lane = t & 63;                                                               \
    const int w = t >> 6;                                                                  \
    const int wm = (w >> 1) * 64, wn = (w & 1) * 64;                                       \
    const int l15 = lane & 15, quad = lane >> 4;                                           \
    const int g0 = t, g1 = 256 + t;                                                        \
    const int r0 = g0 >> 2, r1 = g1 >> 2;                                                  \
    const int c0 = ((g0 & 3) ^ ((r0 >> 1) & 3)) * 8;                                       \
    const int c1 = ((g1 & 3) ^ ((r1 >> 1) & 3)) * 8;                                       \
    for (int k0 = 0; k0 < DM; k0 += 32) {                                                  \
        glds16(&P0[(size_t)(OFF0 + r0) * DM + k0 + c0], &As[g0 * 8]);                      \
        glds16(&P0[(size_t)(OFF0 + r1) * DM + k0 + c1], &As[g1 * 8]);                      \
        glds16(&P1[(size_t)(OFF1 + r0) * DM + k0 + c0], &Bs[g0 * 8]);                      \
        glds16(&P1[(size_t)(OFF1 + r1) * DM + k0 + c1], &Bs[g1 * 8]);                      \
        __syncthreads();                                                                   \
        bf16x8 a[4], b[4];                                                                 \
        _Pragma("unroll")                                                                  \
        for (int i = 0; i < 4; i++) {                                                      \
            int row = wm + i * 16 + l15;                                                   \
            a[i] = *(bf16x8*)&As[row * 32 + (quad ^ ((row >> 1) & 3)) * 8];                \
        }                                                                                  \
        _Pragma("unroll")                                                                  \
        for (int j = 0; j < 4; j++) {                                                      \
            int row = wn + j * 16 + l15;                                                   \
            b[j] = *(bf16x8*)&Bs[row * 32 + (quad ^ ((row >> 1) & 3)) * 8];                \
        }                                                                                  \
        _Pragma("unroll")                                                                  \
        for (int i = 0; i < 4; i++)                                                        \
            _Pragma("unroll")                                                              \
            for (int j = 0; j < 4; j++)                                                    \
                acc[i][j] = __builtin_amdgcn_mfma_f32_16x16x32_bf16(a[i], b[j], acc[i][j], 0, 0, 0); \
        __syncthreads();                                                                   \
    }

// ---------------------------------------------------------------------------
// fused QKV projection GEMM. grid = (8, 64, nz); z = blockIdx.z + zoff.
// XCD-aware tile remap (r5-proven): XCD = id % 8 = blockIdx.x. Remap
// (vx,vy) = (y&7, (x<<3)|(y>>3)) so each XCD owns an 8x8 sub-grid.
// z=0: Q (swapped orient, b64 stores to [bh][s][64], bias*QSCALE)
// z=1: K (same, bias*1)
// z=2: V (normal orient, transposed store [bh][d][s'], s' = slab-permuted col:
//         within each 32-key slab, 4-key group g stored at group bitswap01(g).
//         This makes attn's PV k-slot map realizable with permlane32 only.)
// ---------------------------------------------------------------------------
__global__ __launch_bounds__(256)
void gemm_qkv(const short* __restrict__ x0, const short* __restrict__ x1, const short* __restrict__ x2,
              const short* __restrict__ Wball,
              const float* __restrict__ bq, const float* __restrict__ bk, const float* __restrict__ bv,
              short* __restrict__ qws, short* __restrict__ kws, short* __restrict__ vws,
              int zoff)
{
    const int z = blockIdx.z + zoff;
    const short* X = (z == 0) ? x0 : (z == 1) ? x1 : x2;
    const short* W = Wball + (size_t)z * DM * DM;
    const float* bias = (z == 0) ? bq : (z == 1) ? bk : bv;
    const float bscale = (z == 0) ? QSCALE : 1.0f;

    const int vx = blockIdx.y & 7;
    const int vy = (blockIdx.x << 3) | (blockIdx.y >> 3);
    const int tn = vx * 128;
    const int tm = vy * 128;
    const int vm = (z == 2);

    const short* P0 = vm ? X : W;   const int OFF0 = vm ? tm : tn;
    const short* P1 = vm ? W : X;   const int OFF1 = vm ? tn : tm;
    GEMM_CORE(P0, OFF0, P1, OFF1)

    if (vm) {
        // V: [bh][d][s']; r-regs = 4 consecutive s -> b64 stores, slab-permuted col
#pragma unroll
        for (int j = 0; j < 4; j++) {
            int n = tn + wn + j * 16 + l15;
            float bn = bias[n];
            int h = n >> 6, d = n & 63;
#pragma unroll
            for (int i = 0; i < 4; i++) {
                int m0 = tm + wm + i * 16 + quad * 4;
                int bb = m0 >> 11, s0 = m0 & (SEQ - 1);
                int g = (s0 >> 2) & 7;                              // 4-key group in slab
                int gp = (g & 4) | ((g & 1) << 1) | ((g >> 1) & 1); // bitswap01 (involution)
                int sp = (s0 & ~31) | (gp << 2);
                u32x2 u = { pk2(acc[i][j][0] + bn, acc[i][j][1] + bn),
                            pk2(acc[i][j][2] + bn, acc[i][j][3] + bn) };
                *(u32x2*)&vws[((size_t)((bb * NH + h) * 64 + d)) * SEQ + sp] = u;
            }
        }
    } else {
        short* dst = (z == 0) ? qws : kws;
        // swapped: acc rows = features, cols = tokens -> b64 stores along d
#pragma unroll
        for (int i = 0; i < 4; i++) {
            int n0 = tn + wm + i * 16 + quad * 4;
            float4 b4 = *(const float4*)&bias[n0];
            int h = n0 >> 6, d0 = n0 & 63;
#pragma unroll
            for (int j = 0; j < 4; j++) {
                int m = tm + wn + j * 16 + l15;
                int bb = m >> 11, s = m & (SEQ - 1);
                u32x2 u = { pk2(acc[i][j][0] + b4.x * bscale, acc[i][j][1] + b4.y * bscale),
                            pk2(acc[i][j][2] + b4.z * bscale, acc[i][j][3] + b4.w * bscale) };
                *(u32x2*)&dst[((((size_t)(bb * NH + h)) * SEQ + s) << 6) + d0] = u;
            }
        }
    }
}

__global__ __launch_bounds__(256)
void out_proj(const short* __restrict__ A, const short* __restrict__ W,
              const float* __restrict__ bias, float* __restrict__ out)
{
    // same XCD-aware remap as gemm_qkv (grid (8,64), XCD = blockIdx.x)
    const int vx = blockIdx.y & 7;
    const int vy = (blockIdx.x << 3) | (blockIdx.y >> 3);
    const int tn = vx * 128;
    const int tm = vy * 128;
    GEMM_CORE(A, tm, W, tn)

#pragma unroll
    for (int j = 0; j < 4; j++) {
        int n = tn + wn + j * 16 + l15;
        float bn = bias[n];
#pragma unroll
        for (int i = 0; i < 4; i++)
#pragma unroll
            for (int r = 0; r < 4; r++) {
                int m = tm + wm + i * 16 + quad * 4 + r;
                out[(size_t)m * DM + n] = acc[i][j][r] + bn;
            }
    }
}

// ---------------------------------------------------------------------------
// flash attention, transposed (S^T = K Q^T, O^T = V^T P^T), no-max softmax.
// Softmax denominator via MFMA: Vt row 64 = ones, rows 65..79 = 0;
// O^T row 64 accumulates sum_k P across all tiles (zero per-tile VALU reduce).
//
//  - TLP-FIRST (r7): attn is stall-bound (r6: MfmaUtil 37 + VALUBusy 38,
//    FETCH already minimal). 32 q-rows/wave, grid (8,128) = 1024 blocks =
//    4 blocks/CU = 4 independent waves/SIMD to interleave the serial
//    QK->exp2->pack->PV chains. (q-doubling halved blocks/CU for LDS-read
//    efficiency that no counter showed binding — reverted.)
//  - XCD-aware remap kept (r6-proven: FETCH 139->24.6MB): XCD = id%8 = x;
//    bh = (x<<3)|(y>>4), qt = y&15 -> per-XCD K/V = 4MB = one L2.
//  - P stays IN REGISTERS via cvt_pk + 2x permlane32_swap; V stored with
//    matching slab-permuted columns (see gemm_qkv).
//  - K/V double-buffered in LDS via direct global_load_lds (linear dest,
//    inverse-swizzled global source, unit^(row&7)); ONE barrier per K-tile.
//
// Q,K: bf16 [bh][s][64] (Q pre-scaled); V: bf16 [bh][d][s']; O: [b][s][h*64+d]
// ---------------------------------------------------------------------------
__global__ __launch_bounds__(256, 4)
void attn(const short* __restrict__ Q, const short* __restrict__ K, const short* __restrict__ V,
          short* __restrict__ O)
{
    const int qt = blockIdx.y & 15;
    const int bh = (blockIdx.x << 3) | (blockIdx.y >> 4);
    const int b = bh >> 4, h = bh & 15;
    const size_t base = (size_t)bh * SEQ * DK;
    const size_t vbase = (size_t)bh * DK * SEQ;

    const int t = threadIdx.x;
    const int lane = t & 63;
    const int w = t >> 6;
    const int l15 = lane & 15, quad = lane >> 4;
    const int l7 = l15 & 7;

    __shared__ short Kt[2][64 * 64];   // [buf][key][d], 16B-unit swizzle u^(row&7)
    __shared__ short Vt[2][80 * 64];   // [buf][d][key']; rows 64..79: ones-trick

    // ones rows, both buffers (row 64 = 1.0 bf16, 65..79 = 0); uniform rows -> swizzle-safe
    {
        int buf = t >> 7;
        int row = 64 + ((t >> 3) & 15);
        short val = (row == 64) ? (short)0x3F80 : (short)0;
        bf16x8 fill = { val, val, val, val, val, val, val, val };
        *(bf16x8*)&Vt[buf][row * 64 + (t & 7) * 8] = fill;
    }

    // staging geometry: thread t -> LDS rows {t>>3, 32+(t>>3)}, 16B unit t&7 (linear dest);
    // global source unit pre-swizzled: (t&7) ^ (row&7)  (row&7 identical for both rows)
    const int sr = t >> 3, su = t & 7;
    const int swz = (su ^ (sr & 7)) * 8;
    const short* kp0 = &K[base + (size_t)sr * DK + swz];
    const short* vp0 = &V[vbase + (size_t)sr * SEQ + swz];

    glds16(kp0,               &Kt[0][sr * 64 + su * 8]);
    glds16(kp0 + 32 * DK,     &Kt[0][(32 + sr) * 64 + su * 8]);
    glds16(vp0,               &Vt[0][sr * 64 + su * 8]);
    glds16(vp0 + 32 * SEQ,    &Vt[0][(32 + sr) * 64 + su * 8]);

    bf16x8 qb[2][2];
    const int qrow0 = qt * 128 + w * 32;
#pragma unroll
    for (int nq = 0; nq < 2; nq++)
#pragma unroll
        for (int kd = 0; kd < 2; kd++)
            qb[nq][kd] = *(const bf16x8*)&Q[base + (size_t)(qrow0 + nq * 16 + l15) * DK + kd * 32 + quad * 8];

    f32x4 oT[5][2] = {};

    for (int kt = 0; kt < SEQ / 64; kt++) {
        __syncthreads();   // drains prev glds (vmcnt) + all waves' prev reads (lgkm)
        const int cur = kt & 1;
        if (kt < SEQ / 64 - 1) {
            const int nxt = cur ^ 1;
            const int kb = (kt + 1) * 64;
            glds16(kp0 + (size_t)kb * DK,        &Kt[nxt][sr * 64 + su * 8]);
            glds16(kp0 + (size_t)(kb + 32) * DK, &Kt[nxt][(32 + sr) * 64 + su * 8]);
            glds16(vp0 + kb,                     &Vt[nxt][sr * 64 + su * 8]);
            glds16(vp0 + kb + 32 * SEQ,          &Vt[nxt][(32 + sr) * 64 + su * 8]);
        }

#pragma unroll
        for (int half = 0; half < 2; half++) {
            // S^T = K·Q^T for keys [half*32, half*32+32)
            f32x4 st[2][2] = {};
#pragma unroll
            for (int kd = 0; kd < 2; kd++) {
#pragma unroll
                for (int m2 = 0; m2 < 2; m2++) {
                    const int mf = half * 2 + m2;
                    bf16x8 ka = *(bf16x8*)&Kt[cur][(mf * 16 + l15) * 64 + ((kd * 4 + quad) ^ l7) * 8];
#pragma unroll
                    for (int nq = 0; nq < 2; nq++)
                        st[m2][nq] = __builtin_amdgcn_mfma_f32_16x16x32_bf16(ka, qb[nq][kd], st[m2][nq], 0, 0, 0);
                }
            }

            // exp2 + in-register transpose C-frag -> B-frag (permlane32 only).
            // After the two swaps the dwords give quad q' the slab-permuted key
            // order that V is stored in (see gemm_qkv).
            bf16x8 pb[2];
#pragma unroll
            for (int nq = 0; nq < 2; nq++) {
#pragma unroll
                for (int m2 = 0; m2 < 2; m2++)
#pragma unroll
                    for (int r = 0; r < 4; r++)
                        st[m2][nq][r] = __builtin_amdgcn_exp2f(st[m2][nq][r]);
                unsigned W0 = cvtpk(st[0][nq][0], st[0][nq][1]);   // keys 4q+0,1
                unsigned W1 = cvtpk(st[0][nq][2], st[0][nq][3]);   // keys 4q+2,3
                unsigned W2 = cvtpk(st[1][nq][0], st[1][nq][1]);   // keys 16+4q+0,1
                unsigned W3 = cvtpk(st[1][nq][2], st[1][nq][3]);   // keys 16+4q+2,3
                plswap32(W0, W2);   // -> slab-permuted key order (matches V store)
                plswap32(W1, W3);
                u32x4 uu = { W0, W1, W2, W3 };
                pb[nq] = *(bf16x8*)&uu;
            }

            // O^T += V^T·P^T for this 32-key slab; mfd=4 accumulates sum_k P (ones row)
#pragma unroll
            for (int mfd = 0; mfd < 5; mfd++) {
                bf16x8 va = *(bf16x8*)&Vt[cur][(mfd * 16 + l15) * 64 + ((half * 4 + quad) ^ l7) * 8];
#pragma unroll
                for (int nq = 0; nq < 2; nq++)
                    oT[mfd][nq] = __builtin_amdgcn_mfma_f32_16x16x32_bf16(va, pb[nq], oT[mfd][nq], 0, 0, 0);
            }
        }
    }

    // epilogue: l = D[64][qrow] (held by lane l15, quad 0) -> broadcast via shfl
#pragma unroll
    for (int nq = 0; nq < 2; nq++) {
        float lsum = __shfl(oT[4][nq][0], l15);
        float inv = 1.0f / lsum;
        int s = qrow0 + nq * 16 + l15;
#pragma unroll
        for (int mfd = 0; mfd < 4; mfd++) {
            u32x2 u = { cvtpk(oT[mfd][nq][0] * inv, oT[mfd][nq][1] * inv),
                        cvtpk(oT[mfd][nq][2] * inv, oT[mfd][nq][3] * inv) };
            *(u32x2*)&O[((size_t)(b * SEQ + s)) * DM + h * 64 + mfd * 16 + quad * 4] = u;
        }
    }
}

// ---------------------------------------------------------------------------
extern "C" void kernel_launch(void* const* d_in, const int* in_sizes, int n_in,
                              void* d_out, int out_size, void* d_ws, size_t ws_size,
                              hipStream_t stream)
{
    const float* q_in = (const float*)d_in[0];
    const float* k_in = (const float*)d_in[1];
    const float* v_in = (const float*)d_in[2];
    const float* Wq = (const float*)d_in[3];
    const float* bq = (const float*)d_in[4];
    const float* Wk = (const float*)d_in[5];
    const float* bk = (const float*)d_in[6];
    const float* Wv = (const float*)d_in[7];
    const float* bv = (const float*)d_in[8];
    const float* Wo = (const float*)d_in[9];
    const float* bo = (const float*)d_in[10];
    float* out = (float*)d_out;

    char* ws = (char*)d_ws;
    const size_t MB = (size_t)1024 * 1024;
    // q,k bf16 parked inside d_out (32 MB fp32), dead before out_proj writes it
    short* qws = (short*)d_out;
    short* kws = (short*)d_out + (size_t)8 * MB;
    const size_t NW = (size_t)DM * DM;

    if (ws_size >= 88 * MB) {
        // fused path: xb0 16 | xb1 16 | xb2 16 | vws 16 | ows 16 | Wb 8
        short* xb0 = (short*)(ws);
        short* xb1 = (short*)(ws + 16 * MB);
        short* xb2 = (short*)(ws + 32 * MB);
        short* vws = (short*)(ws + 48 * MB);
        short* ows = (short*)(ws + 64 * MB);
        short* Wb  = (short*)(ws + 80 * MB);

        cvt_all<<<dim3(14336), 256, 0, stream>>>(q_in, k_in, v_in, Wq, Wk, Wv, Wo, xb0, xb1, xb2, Wb);
        gemm_qkv<<<dim3(8, 64, 3), 256, 0, stream>>>(xb0, xb1, xb2, Wb, bq, bk, bv, qws, kws, vws, 0);
        attn<<<dim3(8, 128), 256, 0, stream>>>(qws, kws, vws, ows);
        out_proj<<<dim3(8, 64), 256, 0, stream>>>(ows, Wb + 3 * NW, bo, out);
    } else {
        // sequential fallback: xb 16 | vws 16 | ows 16 | Wb 8  (56 MB)
        short* xb  = (short*)(ws);
        short* vws = (short*)(ws + 16 * MB);
        short* ows = (short*)(ws + 32 * MB);
        short* Wb  = (short*)(ws + 48 * MB);
        const int xblocks = (4 * SEQ * DM) / 2048;

        cvt_w<<<dim3((int)(NW / 2048), 4), 256, 0, stream>>>(Wq, Wk, Wv, Wo, Wb);
        cvt_x<<<dim3(xblocks), 256, 0, stream>>>(q_in, xb);
        gemm_qkv<<<dim3(8, 64, 1), 256, 0, stream>>>(xb, xb, xb, Wb, bq, bk, bv, qws, kws, vws, 0);
        cvt_x<<<dim3(xblocks), 256, 0, stream>>>(k_in, xb);
        gemm_qkv<<<dim3(8, 64, 1), 256, 0, stream>>>(xb, xb, xb, Wb, bq, bk, bv, qws, kws, vws, 1);
        cvt_x<<<dim3(xblocks), 256, 0, stream>>>(v_in, xb);
        gemm_qkv<<<dim3(8, 64, 1), 256, 0, stream>>>(xb, xb, xb, Wb, bq, bk, bv, qws, kws, vws, 2);
        attn<<<dim3(8, 128), 256, 0, stream>>>(qws, kws, vws, ows);
        out_proj<<<dim3(8, 64), 256, 0, stream>>>(ows, Wb + 3 * NW, bo, out);
    }
}

// Round 8
// 323.378 us; speedup vs baseline: 1.0369x; 1.0369x over previous
//
#include <hip/hip_runtime.h>
#include <hip/hip_bf16.h>
#include <cstdint>
#include <cstddef>

typedef __attribute__((ext_vector_type(8))) short bf16x8;
typedef __attribute__((ext_vector_type(4))) short bf16x4;
typedef __attribute__((ext_vector_type(4))) float f32x4;
typedef __attribute__((ext_vector_type(2))) unsigned int u32x2;
typedef __attribute__((ext_vector_type(4))) unsigned int u32x4;

#define NH 16
#define DK 64
#define SEQ 2048
#define DM 1024
#define QSCALE 0.18033688011112042f  // 0.125 * log2(e): softmax uses exp2

// RTNE (cvt kernels, VALU free there)
__device__ __forceinline__ short f2bf(float f) {
    union { float f; unsigned u; } x; x.f = f;
    unsigned r = x.u + 0x7fffu + ((x.u >> 16) & 1u);
    return (short)(r >> 16);
}

// fast pack: two f32 -> bf16 pair (round-half-up), one v_perm_b32
__device__ __forceinline__ unsigned pk2(float a, float b) {
    union { float f; unsigned u; } x, y; x.f = a; y.f = b;
    return __builtin_amdgcn_perm(y.u + 0x8000u, x.u + 0x8000u, 0x07060302u);
}

// single-instruction pack: dst.lo16 = bf16(a), dst.hi16 = bf16(b)
__device__ __forceinline__ unsigned cvtpk(float a, float b) {
    unsigned r;
    asm("v_cvt_pk_bf16_f32 %0, %1, %2" : "=v"(r) : "v"(a), "v"(b));
    return r;
}

// gfx950 cross-lane swap (HW direction verified via HK T12 recipe):
// a lanes[32:63] <-> b lanes[0:31]; after: a = (a_lo, b_lo), b = (a_hi, b_hi)
__device__ __forceinline__ void plswap32(unsigned& a, unsigned& b) {
    asm("v_permlane32_swap_b32 %0, %1" : "+v"(a), "+v"(b));
}

__device__ __forceinline__ void glds16(const short* g, short* l) {
    __builtin_amdgcn_global_load_lds((const __attribute__((address_space(1))) unsigned int*)g,
                                     (__attribute__((address_space(3))) unsigned int*)l, 16, 0, 0);
}

// ---------------------------------------------------------------------------
// fused fp32->bf16 conversion: 3 x-inputs (4096 blocks each) + 4 weights (512 each)
// ---------------------------------------------------------------------------
__global__ __launch_bounds__(256)
void cvt_all(const float* __restrict__ xq, const float* __restrict__ xk, const float* __restrict__ xv,
             const float* __restrict__ Wq, const float* __restrict__ Wk,
             const float* __restrict__ Wv, const float* __restrict__ Wo,
             short* __restrict__ xb0, short* __restrict__ xb1, short* __restrict__ xb2,
             short* __restrict__ Wb)
{
    const int bid = blockIdx.x;
    const float* src;
    short* dst;
    float sc = 1.0f;
    int i;
    if (bid < 12288) {
        int z = bid >> 12;
        src = (z == 0) ? xq : (z == 1) ? xk : xv;
        dst = (z == 0) ? xb0 : (z == 1) ? xb1 : xb2;
        i = (bid & 4095) * 2048 + threadIdx.x * 8;
    } else {
        int wb = bid - 12288;
        int z = wb >> 9;
        src = (z == 0) ? Wq : (z == 1) ? Wk : (z == 2) ? Wv : Wo;
        dst = Wb + (size_t)z * DM * DM;
        sc = (z == 0) ? QSCALE : 1.0f;  // fold q scale into Wq
        i = (wb & 511) * 2048 + threadIdx.x * 8;
    }
    float4 a = *(const float4*)&src[i];
    float4 b = *(const float4*)&src[i + 4];
    bf16x8 o = { f2bf(a.x * sc), f2bf(a.y * sc), f2bf(a.z * sc), f2bf(a.w * sc),
                 f2bf(b.x * sc), f2bf(b.y * sc), f2bf(b.z * sc), f2bf(b.w * sc) };
    *(bf16x8*)&dst[i] = o;
}

// fallback converters (sequential path)
__global__ __launch_bounds__(256)
void cvt_x(const float* __restrict__ src, short* __restrict__ dst)
{
    int i = (blockIdx.x * 256 + threadIdx.x) * 8;
    float4 a = *(const float4*)&src[i];
    float4 b = *(const float4*)&src[i + 4];
    bf16x8 o = { f2bf(a.x), f2bf(a.y), f2bf(a.z), f2bf(a.w),
                 f2bf(b.x), f2bf(b.y), f2bf(b.z), f2bf(b.w) };
    *(bf16x8*)&dst[i] = o;
}

__global__ __launch_bounds__(256)
void cvt_w(const float* __restrict__ Wq, const float* __restrict__ Wk,
           const float* __restrict__ Wv, const float* __restrict__ Wo,
           short* __restrict__ dst)
{
    int z = blockIdx.y;
    const float* s = (z == 0) ? Wq : (z == 1) ? Wk : (z == 2) ? Wv : Wo;
    float sc = (z == 0) ? QSCALE : 1.0f;
    int i = (blockIdx.x * 256 + threadIdx.x) * 8;
    float4 a = *(const float4*)&s[i];
    float4 b = *(const float4*)&s[i + 4];
    bf16x8 o = { f2bf(a.x * sc), f2bf(a.y * sc), f2bf(a.z * sc), f2bf(a.w * sc),
                 f2bf(b.x * sc), f2bf(b.y * sc), f2bf(b.z * sc), f2bf(b.w * sc) };
    *(bf16x8*)&dst[(size_t)z * DM * DM + i] = o;
}

// ---------------------------------------------------------------------------
// bf16 GEMM core: 128x128 tile, BK=64 (r8), global_load_lds width=16.
// BK 32->64 halves the vmcnt(0)+barrier drain EVENTS (32->16 K-steps) while
// MFMA/LDS-read totals stay constant — m233: the 2-phase stall is the
// dominant cost (MfmaUtil 25%). LDS 32 KB; kd-structured inner loop keeps
// only 8 live frags. Swizzle = attn's proven Kt pattern: 64-short rows,
// read unit (kd*4+quad)^l7; staging dest linear (uniform + lane*16, m104),
// global source col pre-swizzled (su^(sr&7)).
// ---------------------------------------------------------------------------
#define GEMM_CORE(P0, OFF0, P1, OFF1)                                                      \
    __shared__ short As[128 * 64];                                                         \
    __shared__ short Bs[128 * 64];                                                         \
    f32x4 acc[4][4] = {};                                                                  \
    const int t = threadIdx.x;                                                             \
    const int lane = t & 63;                                                               \
    const int w = t >> 6;                                                                  \
    const int wm = (w >> 1) * 64, wn = (w & 1) * 64;                                       \
    const int l15 = lane & 15, quad = lane >> 4;                                           \
    const int l7 = l15 & 7;                                                                \
    const int sr = t >> 3, su = t & 7;                                                     \
    const int sc8 = (su ^ (sr & 7)) * 8;                                                   \
    for (int k0 = 0; k0 < DM; k0 += 64) {                                                  \
        _Pragma("unroll")                                                                  \
        for (int p = 0; p < 4; p++) {                                                      \
            glds16(&P0[(size_t)(OFF0 + sr + p * 32) * DM + k0 + sc8], &As[(sr + p * 32) * 64 + su * 8]); \
            glds16(&P1[(size_t)(OFF1 + sr + p * 32) * DM + k0 + sc8], &Bs[(sr + p * 32) * 64 + su * 8]); \
        }                                                                                  \
        __syncthreads();                                                                   \
        _Pragma("unroll")                                                                  \
        for (int kd = 0; kd < 2; kd++) {                                                   \
            bf16x8 a[4], b[4];                                                             \
            _Pragma("unroll")                                                              \
            for (int i = 0; i < 4; i++)                                                    \
                a[i] = *(bf16x8*)&As[(wm + i * 16 + l15) * 64 + ((kd * 4 + quad) ^ l7) * 8]; \
            _Pragma("unroll")                                                              \
            for (int j = 0; j < 4; j++)                                                    \
                b[j] = *(bf16x8*)&Bs[(wn + j * 16 + l15) * 64 + ((kd * 4 + quad) ^ l7) * 8]; \
            _Pragma("unroll")                                                              \
            for (int i = 0; i < 4; i++)                                                    \
                _Pragma("unroll")                                                          \
                for (int j = 0; j < 4; j++)                                                \
                    acc[i][j] = __builtin_amdgcn_mfma_f32_16x16x32_bf16(a[i], b[j], acc[i][j], 0, 0, 0); \
        }                                                                                  \
        __syncthreads();                                                                   \
    }

// ---------------------------------------------------------------------------
// fused QKV projection GEMM. grid = (8, 64, nz); z = blockIdx.z + zoff.
// XCD-aware tile remap (r5-proven): XCD = id % 8 = blockIdx.x. Remap
// (vx,vy) = (y&7, (x<<3)|(y>>3)) so each XCD owns an 8x8 sub-grid.
// z=0: Q (swapped orient, b64 stores to [bh][s][64], bias*QSCALE)
// z=1: K (same, bias*1)
// z=2: V (normal orient, transposed store [bh][d][s'], s' = slab-permuted col:
//         within each 32-key slab, 4-key group g stored at group bitswap01(g).
//         This makes attn's PV k-slot map realizable with permlane32 only.)
// ---------------------------------------------------------------------------
__global__ __launch_bounds__(256)
void gemm_qkv(const short* __restrict__ x0, const short* __restrict__ x1, const short* __restrict__ x2,
              const short* __restrict__ Wball,
              const float* __restrict__ bq, const float* __restrict__ bk, const float* __restrict__ bv,
              short* __restrict__ qws, short* __restrict__ kws, short* __restrict__ vws,
              int zoff)
{
    const int z = blockIdx.z + zoff;
    const short* X = (z == 0) ? x0 : (z == 1) ? x1 : x2;
    const short* W = Wball + (size_t)z * DM * DM;
    const float* bias = (z == 0) ? bq : (z == 1) ? bk : bv;
    const float bscale = (z == 0) ? QSCALE : 1.0f;

    const int vx = blockIdx.y & 7;
    const int vy = (blockIdx.x << 3) | (blockIdx.y >> 3);
    const int tn = vx * 128;
    const int tm = vy * 128;
    const int vm = (z == 2);

    const short* P0 = vm ? X : W;   const int OFF0 = vm ? tm : tn;
    const short* P1 = vm ? W : X;   const int OFF1 = vm ? tn : tm;
    GEMM_CORE(P0, OFF0, P1, OFF1)

    if (vm) {
        // V: [bh][d][s']; r-regs = 4 consecutive s -> b64 stores, slab-permuted col
#pragma unroll
        for (int j = 0; j < 4; j++) {
            int n = tn + wn + j * 16 + l15;
            float bn = bias[n];
            int h = n >> 6, d = n & 63;
#pragma unroll
            for (int i = 0; i < 4; i++) {
                int m0 = tm + wm + i * 16 + quad * 4;
                int bb = m0 >> 11, s0 = m0 & (SEQ - 1);
                int g = (s0 >> 2) & 7;                              // 4-key group in slab
                int gp = (g & 4) | ((g & 1) << 1) | ((g >> 1) & 1); // bitswap01 (involution)
                int sp = (s0 & ~31) | (gp << 2);
                u32x2 u = { pk2(acc[i][j][0] + bn, acc[i][j][1] + bn),
                            pk2(acc[i][j][2] + bn, acc[i][j][3] + bn) };
                *(u32x2*)&vws[((size_t)((bb * NH + h) * 64 + d)) * SEQ + sp] = u;
            }
        }
    } else {
        short* dst = (z == 0) ? qws : kws;
        // swapped: acc rows = features, cols = tokens -> b64 stores along d
#pragma unroll
        for (int i = 0; i < 4; i++) {
            int n0 = tn + wm + i * 16 + quad * 4;
            float4 b4 = *(const float4*)&bias[n0];
            int h = n0 >> 6, d0 = n0 & 63;
#pragma unroll
            for (int j = 0; j < 4; j++) {
                int m = tm + wn + j * 16 + l15;
                int bb = m >> 11, s = m & (SEQ - 1);
                u32x2 u = { pk2(acc[i][j][0] + b4.x * bscale, acc[i][j][1] + b4.y * bscale),
                            pk2(acc[i][j][2] + b4.z * bscale, acc[i][j][3] + b4.w * bscale) };
                *(u32x2*)&dst[((((size_t)(bb * NH + h)) * SEQ + s) << 6) + d0] = u;
            }
        }
    }
}

__global__ __launch_bounds__(256)
void out_proj(const short* __restrict__ A, const short* __restrict__ W,
              const float* __restrict__ bias, float* __restrict__ out)
{
    // same XCD-aware remap as gemm_qkv (grid (8,64), XCD = blockIdx.x)
    const int vx = blockIdx.y & 7;
    const int vy = (blockIdx.x << 3) | (blockIdx.y >> 3);
    const int tn = vx * 128;
    const int tm = vy * 128;
    GEMM_CORE(A, tm, W, tn)

#pragma unroll
    for (int j = 0; j < 4; j++) {
        int n = tn + wn + j * 16 + l15;
        float bn = bias[n];
#pragma unroll
        for (int i = 0; i < 4; i++)
#pragma unroll
            for (int r = 0; r < 4; r++) {
                int m = tm + wm + i * 16 + quad * 4 + r;
                out[(size_t)m * DM + n] = acc[i][j][r] + bn;
            }
    }
}

// ---------------------------------------------------------------------------
// flash attention, transposed (S^T = K Q^T, O^T = V^T P^T), no-max softmax.
// Softmax denominator via MFMA: Vt row 64 = ones, rows 65..79 = 0;
// O^T row 64 accumulates sum_k P across all tiles (zero per-tile VALU reduce).
//
//  - TLP (r7-proven): 32 q-rows/wave, grid (8,128) = 4 blocks/CU.
//  - T5 setprio (r8): MFMA clusters wrapped in s_setprio(1)/(0) — 4
//    independent blocks/CU = phase-diverse waves, the regime T5 needs
//    (m191: +4-7% attn).
//  - XCD-aware remap (r6-proven: FETCH 139->24.6MB): bh = (x<<3)|(y>>4).
//  - P stays IN REGISTERS via cvt_pk + 2x permlane32_swap; V stored with
//    matching slab-permuted columns (see gemm_qkv).
//  - K/V double-buffered in LDS via direct global_load_lds; ONE barrier/K-tile.
//
// Q,K: bf16 [bh][s][64] (Q pre-scaled); V: bf16 [bh][d][s']; O: [b][s][h*64+d]
// ---------------------------------------------------------------------------
__global__ __launch_bounds__(256, 4)
void attn(const short* __restrict__ Q, const short* __restrict__ K, const short* __restrict__ V,
          short* __restrict__ O)
{
    const int qt = blockIdx.y & 15;
    const int bh = (blockIdx.x << 3) | (blockIdx.y >> 4);
    const int b = bh >> 4, h = bh & 15;
    const size_t base = (size_t)bh * SEQ * DK;
    const size_t vbase = (size_t)bh * DK * SEQ;

    const int t = threadIdx.x;
    const int lane = t & 63;
    const int w = t >> 6;
    const int l15 = lane & 15, quad = lane >> 4;
    const int l7 = l15 & 7;

    __shared__ short Kt[2][64 * 64];   // [buf][key][d], 16B-unit swizzle u^(row&7)
    __shared__ short Vt[2][80 * 64];   // [buf][d][key']; rows 64..79: ones-trick

    // ones rows, both buffers (row 64 = 1.0 bf16, 65..79 = 0); uniform rows -> swizzle-safe
    {
        int buf = t >> 7;
        int row = 64 + ((t >> 3) & 15);
        short val = (row == 64) ? (short)0x3F80 : (short)0;
        bf16x8 fill = { val, val, val, val, val, val, val, val };
        *(bf16x8*)&Vt[buf][row * 64 + (t & 7) * 8] = fill;
    }

    // staging geometry: thread t -> LDS rows {t>>3, 32+(t>>3)}, 16B unit t&7 (linear dest);
    // global source unit pre-swizzled: (t&7) ^ (row&7)  (row&7 identical for both rows)
    const int sr = t >> 3, su = t & 7;
    const int swz = (su ^ (sr & 7)) * 8;
    const short* kp0 = &K[base + (size_t)sr * DK + swz];
    const short* vp0 = &V[vbase + (size_t)sr * SEQ + swz];

    glds16(kp0,               &Kt[0][sr * 64 + su * 8]);
    glds16(kp0 + 32 * DK,     &Kt[0][(32 + sr) * 64 + su * 8]);
    glds16(vp0,               &Vt[0][sr * 64 + su * 8]);
    glds16(vp0 + 32 * SEQ,    &Vt[0][(32 + sr) * 64 + su * 8]);

    bf16x8 qb[2][2];
    const int qrow0 = qt * 128 + w * 32;
#pragma unroll
    for (int nq = 0; nq < 2; nq++)
#pragma unroll
        for (int kd = 0; kd < 2; kd++)
            qb[nq][kd] = *(const bf16x8*)&Q[base + (size_t)(qrow0 + nq * 16 + l15) * DK + kd * 32 + quad * 8];

    f32x4 oT[5][2] = {};

    for (int kt = 0; kt < SEQ / 64; kt++) {
        __syncthreads();   // drains prev glds (vmcnt) + all waves' prev reads (lgkm)
        const int cur = kt & 1;
        if (kt < SEQ / 64 - 1) {
            const int nxt = cur ^ 1;
            const int kb = (kt + 1) * 64;
            glds16(kp0 + (size_t)kb * DK,        &Kt[nxt][sr * 64 + su * 8]);
            glds16(kp0 + (size_t)(kb + 32) * DK, &Kt[nxt][(32 + sr) * 64 + su * 8]);
            glds16(vp0 + kb,                     &Vt[nxt][sr * 64 + su * 8]);
            glds16(vp0 + kb + 32 * SEQ,          &Vt[nxt][(32 + sr) * 64 + su * 8]);
        }

#pragma unroll
        for (int half = 0; half < 2; half++) {
            // S^T = K·Q^T for keys [half*32, half*32+32)
            f32x4 st[2][2] = {};
            __builtin_amdgcn_s_setprio(1);
#pragma unroll
            for (int kd = 0; kd < 2; kd++) {
#pragma unroll
                for (int m2 = 0; m2 < 2; m2++) {
                    const int mf = half * 2 + m2;
                    bf16x8 ka = *(bf16x8*)&Kt[cur][(mf * 16 + l15) * 64 + ((kd * 4 + quad) ^ l7) * 8];
#pragma unroll
                    for (int nq = 0; nq < 2; nq++)
                        st[m2][nq] = __builtin_amdgcn_mfma_f32_16x16x32_bf16(ka, qb[nq][kd], st[m2][nq], 0, 0, 0);
                }
            }
            __builtin_amdgcn_s_setprio(0);

            // exp2 + in-register transpose C-frag -> B-frag (permlane32 only).
            // After the two swaps the dwords give quad q' the slab-permuted key
            // order that V is stored in (see gemm_qkv).
            bf16x8 pb[2];
#pragma unroll
            for (int nq = 0; nq < 2; nq++) {
#pragma unroll
                for (int m2 = 0; m2 < 2; m2++)
#pragma unroll
                    for (int r = 0; r < 4; r++)
                        st[m2][nq][r] = __builtin_amdgcn_exp2f(st[m2][nq][r]);
                unsigned W0 = cvtpk(st[0][nq][0], st[0][nq][1]);   // keys 4q+0,1
                unsigned W1 = cvtpk(st[0][nq][2], st[0][nq][3]);   // keys 4q+2,3
                unsigned W2 = cvtpk(st[1][nq][0], st[1][nq][1]);   // keys 16+4q+0,1
                unsigned W3 = cvtpk(st[1][nq][2], st[1][nq][3]);   // keys 16+4q+2,3
                plswap32(W0, W2);   // -> slab-permuted key order (matches V store)
                plswap32(W1, W3);
                u32x4 uu = { W0, W1, W2, W3 };
                pb[nq] = *(bf16x8*)&uu;
            }

            // O^T += V^T·P^T for this 32-key slab; mfd=4 accumulates sum_k P (ones row)
            __builtin_amdgcn_s_setprio(1);
#pragma unroll
            for (int mfd = 0; mfd < 5; mfd++) {
                bf16x8 va = *(bf16x8*)&Vt[cur][(mfd * 16 + l15) * 64 + ((half * 4 + quad) ^ l7) * 8];
#pragma unroll
                for (int nq = 0; nq < 2; nq++)
                    oT[mfd][nq] = __builtin_amdgcn_mfma_f32_16x16x32_bf16(va, pb[nq], oT[mfd][nq], 0, 0, 0);
            }
            __builtin_amdgcn_s_setprio(0);
        }
    }

    // epilogue: l = D[64][qrow] (held by lane l15, quad 0) -> broadcast via shfl
#pragma unroll
    for (int nq = 0; nq < 2; nq++) {
        float lsum = __shfl(oT[4][nq][0], l15);
        float inv = 1.0f / lsum;
        int s = qrow0 + nq * 16 + l15;
#pragma unroll
        for (int mfd = 0; mfd < 4; mfd++) {
            u32x2 u = { cvtpk(oT[mfd][nq][0] * inv, oT[mfd][nq][1] * inv),
                        cvtpk(oT[mfd][nq][2] * inv, oT[mfd][nq][3] * inv) };
            *(u32x2*)&O[((size_t)(b * SEQ + s)) * DM + h * 64 + mfd * 16 + quad * 4] = u;
        }
    }
}

// ---------------------------------------------------------------------------
extern "C" void kernel_launch(void* const* d_in, const int* in_sizes, int n_in,
                              void* d_out, int out_size, void* d_ws, size_t ws_size,
                              hipStream_t stream)
{
    const float* q_in = (const float*)d_in[0];
    const float* k_in = (const float*)d_in[1];
    const float* v_in = (const float*)d_in[2];
    const float* Wq = (const float*)d_in[3];
    const float* bq = (const float*)d_in[4];
    const float* Wk = (const float*)d_in[5];
    const float* bk = (const float*)d_in[6];
    const float* Wv = (const float*)d_in[7];
    const float* bv = (const float*)d_in[8];
    const float* Wo = (const float*)d_in[9];
    const float* bo = (const float*)d_in[10];
    float* out = (float*)d_out;

    char* ws = (char*)d_ws;
    const size_t MB = (size_t)1024 * 1024;
    // q,k bf16 parked inside d_out (32 MB fp32), dead before out_proj writes it
    short* qws = (short*)d_out;
    short* kws = (short*)d_out + (size_t)8 * MB;
    const size_t NW = (size_t)DM * DM;

    if (ws_size >= 88 * MB) {
        // fused path: xb0 16 | xb1 16 | xb2 16 | vws 16 | ows 16 | Wb 8
        short* xb0 = (short*)(ws);
        short* xb1 = (short*)(ws + 16 * MB);
        short* xb2 = (short*)(ws + 32 * MB);
        short* vws = (short*)(ws + 48 * MB);
        short* ows = (short*)(ws + 64 * MB);
        short* Wb  = (short*)(ws + 80 * MB);

        cvt_all<<<dim3(14336), 256, 0, stream>>>(q_in, k_in, v_in, Wq, Wk, Wv, Wo, xb0, xb1, xb2, Wb);
        gemm_qkv<<<dim3(8, 64, 3), 256, 0, stream>>>(xb0, xb1, xb2, Wb, bq, bk, bv, qws, kws, vws, 0);
        attn<<<dim3(8, 128), 256, 0, stream>>>(qws, kws, vws, ows);
        out_proj<<<dim3(8, 64), 256, 0, stream>>>(ows, Wb + 3 * NW, bo, out);
    } else {
        // sequential fallback: xb 16 | vws 16 | ows 16 | Wb 8  (56 MB)
        short* xb  = (short*)(ws);
        short* vws = (short*)(ws + 16 * MB);
        short* ows = (short*)(ws + 32 * MB);
        short* Wb  = (short*)(ws + 48 * MB);
        const int xblocks = (4 * SEQ * DM) / 2048;

        cvt_w<<<dim3((int)(NW / 2048), 4), 256, 0, stream>>>(Wq, Wk, Wv, Wo, Wb);
        cvt_x<<<dim3(xblocks), 256, 0, stream>>>(q_in, xb);
        gemm_qkv<<<dim3(8, 64, 1), 256, 0, stream>>>(xb, xb, xb, Wb, bq, bk, bv, qws, kws, vws, 0);
        cvt_x<<<dim3(xblocks), 256, 0, stream>>>(k_in, xb);
        gemm_qkv<<<dim3(8, 64, 1), 256, 0, stream>>>(xb, xb, xb, Wb, bq, bk, bv, qws, kws, vws, 1);
        cvt_x<<<dim3(xblocks), 256, 0, stream>>>(v_in, xb);
        gemm_qkv<<<dim3(8, 64, 1), 256, 0, stream>>>(xb, xb, xb, Wb, bq, bk, bv, qws, kws, vws, 2);
        attn<<<dim3(8, 128), 256, 0, stream>>>(qws, kws, vws, ows);
        out_proj<<<dim3(8, 64), 256, 0, stream>>>(ows, Wb + 3 * NW, bo, out);
    }
}